// Round 12
// baseline (89.947 us; speedup 1.0000x reference)
//
#include <hip/hip_runtime.h>
#include <math.h>

#define N 6144
#define E 64
#define H 8
#define D 512
#define TD 1536  // 3*D
#define EPS 1e-5f
#define SCALE 0.04419417382415922f  // 1/sqrt(512)
#define RMAX 80                     // max supported segment size

typedef __attribute__((ext_vector_type(8))) short bf16x8;
typedef __attribute__((ext_vector_type(4))) float f32x4;

static __device__ __forceinline__ unsigned short f2bf(float f) {
    union { float f; unsigned int u; } v; v.f = f;
    unsigned int r = v.u + 0x7FFFu + ((v.u >> 16) & 1u);  // RNE
    return (unsigned short)(r >> 16);
}
static __device__ __forceinline__ float bf2f(unsigned short u) {
    union { unsigned int u; float f; } v; v.u = ((unsigned int)u) << 16;
    return v.f;
}

// ---------------------------------------------------------------------------
// Kernel 0: prep. Blocks [0,32): bound table + Wt/Wot bf16 transposes +
// cnt[] zeroing (block 0). Blocks [32,1568): LN1 -> h1 bf16 [N][64], one row
// per wave (full parallelism — R10 lesson: per-block LN1 recompute regressed).
// ---------------------------------------------------------------------------
__global__ __launch_bounds__(256) void prep_kernel(
    const float* __restrict__ x, const float* __restrict__ ln1g,
    const float* __restrict__ ln1b, const float* __restrict__ W_qkv,
    const float* __restrict__ W_out, const int* __restrict__ batch,
    unsigned short* __restrict__ Wt, unsigned short* __restrict__ Wot,
    int* __restrict__ bound, unsigned short* __restrict__ h1g,
    int* __restrict__ cnt)
{
    const int t = threadIdx.x, lane = t & 63, wv = t >> 6;
    if (blockIdx.x < 32) {
        const int tid = blockIdx.x * 256 + t;
        if (blockIdx.x == 0) cnt[t] = 0;               // re-zero every call
        if (tid < N) {
            const int bv = batch[tid];
            const int prev = tid ? batch[tid - 1] : -1;
            if (bv != prev)
                for (int v = prev + 1; v <= bv; ++v) bound[v] = tid;
            if (tid == N - 1)
                for (int v = bv + 1; v <= 256; ++v) bound[v] = N;
        }
        for (int i = tid; i < 64 * TD; i += 8192) {    // Wt[j][k] = W[k][j]
            const int k = i / TD, j = i - k * TD;
            Wt[j * 64 + k] = f2bf(W_qkv[i]);
        }
        for (int i = tid; i < 512 * 64; i += 8192) {   // Wot[j][k] = Wo[k][j]
            const int k = i >> 6, j = i & 63;
            Wot[j * 512 + k] = f2bf(W_out[i]);
        }
    } else {
        const int row = (blockIdx.x - 32) * 4 + wv;    // [0, 6144)
        const float v = x[(size_t)row * E + lane];
        float sm = v, sq = v * v;
        #pragma unroll
        for (int off = 1; off < 64; off <<= 1) {
            sm += __shfl_xor(sm, off);
            sq += __shfl_xor(sq, off);
        }
        const float mean = sm * (1.f / 64.f);
        const float var  = sq * (1.f / 64.f) - mean * mean;
        h1g[(size_t)row * 64 + lane] =
            f2bf((v - mean) * rsqrtf(var + EPS) * ln1g[lane] + ln1b[lane]);
    }
}

// ---------------------------------------------------------------------------
// Kernel 1: one block per (segment, head). QKV -> attention -> attb (as R11),
// then per-segment completion counter: the 8th block to finish (winner) does
// LN2 + out-projection for the segment's rows, reusing dead Ps LDS as the
// LN2 tile. Flat id = b + 256h, 256%8==0 -> all 8 blocks of a segment on one
// XCD (same L2) under round-robin; correctness guarded by ACQ_REL
// device-scope atomics regardless of mapping. Frag maps (verified R3-R11):
// A[row=lr][k=lg*8+j], B[col=lr][k=lg*8+j], D[col=lr][row=lg*4+r].
// ---------------------------------------------------------------------------
__global__ __launch_bounds__(256) void seghead_kernel(
    const unsigned short* __restrict__ h1g, const unsigned short* __restrict__ Wt,
    const float* __restrict__ b_qkv, const int* __restrict__ bound,
    unsigned short* __restrict__ attb, const float* __restrict__ ln2g,
    const float* __restrict__ ln2b, const unsigned short* __restrict__ Wot,
    const float* __restrict__ b_out, float* __restrict__ y,
    int* __restrict__ cnt)
{
    __shared__ unsigned short Qs[RMAX][72];     // per-head Q [q][d]
    __shared__ unsigned short Ks[RMAX][72];     // per-head K [key][d]
    __shared__ unsigned short Vs[64][104];      // per-head V^T [d][key]
    __shared__ __align__(16) unsigned short Ps[RMAX][104];  // P / O bounce / h2
    __shared__ int amWinner;

    const int t = threadIdx.x, lane = t & 63, wv = t >> 6;
    const int lr = lane & 15, lg = lane >> 4;
    const int b = blockIdx.x, h = blockIdx.y;

    // bound loads first: longest scalar dependency chain (R -> NT/KB/loops)
    const int s = bound[b];
    const int e = bound[b + 1];

    // W fragments for this wave's column tile (overlap under bound latency)
    const int ct = wv;
    const int jK = h * 64 + ct * 16;
    const int jQ = 512 + jK;
    const int jV = 1024 + jK;
    const bf16x8 wK0 = *(const bf16x8*)&Wt[(size_t)(jK + lr) * 64 + lg * 8];
    const bf16x8 wK1 = *(const bf16x8*)&Wt[(size_t)(jK + lr) * 64 + 32 + lg * 8];
    const bf16x8 wQ0 = *(const bf16x8*)&Wt[(size_t)(jQ + lr) * 64 + lg * 8];
    const bf16x8 wQ1 = *(const bf16x8*)&Wt[(size_t)(jQ + lr) * 64 + 32 + lg * 8];
    const bf16x8 wV0 = *(const bf16x8*)&Wt[(size_t)(jV + lr) * 64 + lg * 8];
    const bf16x8 wV1 = *(const bf16x8*)&Wt[(size_t)(jV + lr) * 64 + 32 + lg * 8];
    const float bK = b_qkv[jK + lr];
    const float bQ = b_qkv[jQ + lr];
    const float bV = b_qkv[jV + lr];

    int R = e - s;
    if (R <= 0) return;                 // R==0 segments: no rows, no winner
    if (R > RMAX) R = RMAX;             // safety clamp (P ~ 1e-19)
    const int NT = (R + 15) >> 4;       // 16-row tiles (1..5)
    const int RT = NT * 16;
    const int KB = (RT + 31) >> 5;      // 32-key blocks

    // zero V^T tail key-cols [RT, KB*32): uninitialized LDS there can hold
    // NaN bit-patterns and PV's 0*NaN would poison the accumulator (R7 bug).
    if (RT < KB * 32) {
        for (int idx = t; idx < 64 * 16; idx += 256) {
            const int dd = idx >> 4, cc = RT + (idx & 15);
            if (cc < KB * 32) Vs[dd][cc] = 0;
        }
    }

    // ---- QKV: one pass over row-tiles; K,Q,V together ----
    #pragma unroll
    for (int rt = 0; rt < 5; ++rt) {
        if (rt < NT) {
            int row = s + rt * 16 + lr;
            row = row < N ? row : N - 1;              // clamp (finite data)
            const bf16x8 a0 = *(const bf16x8*)&h1g[(size_t)row * 64 + lg * 8];
            const bf16x8 a1 = *(const bf16x8*)&h1g[(size_t)row * 64 + 32 + lg * 8];
            f32x4 dK = {0,0,0,0}, dQ = {0,0,0,0}, dV = {0,0,0,0};
            dK = __builtin_amdgcn_mfma_f32_16x16x32_bf16(a0, wK0, dK, 0, 0, 0);
            dK = __builtin_amdgcn_mfma_f32_16x16x32_bf16(a1, wK1, dK, 0, 0, 0);
            dQ = __builtin_amdgcn_mfma_f32_16x16x32_bf16(a0, wQ0, dQ, 0, 0, 0);
            dQ = __builtin_amdgcn_mfma_f32_16x16x32_bf16(a1, wQ1, dQ, 0, 0, 0);
            dV = __builtin_amdgcn_mfma_f32_16x16x32_bf16(a0, wV0, dV, 0, 0, 0);
            dV = __builtin_amdgcn_mfma_f32_16x16x32_bf16(a1, wV1, dV, 0, 0, 0);
            const int n4 = rt * 16 + lg * 4;
            #pragma unroll
            for (int r = 0; r < 4; ++r) {
                Ks[n4 + r][ct * 16 + lr] = f2bf(dK[r] + bK);
                Qs[n4 + r][ct * 16 + lr] = f2bf(dQ[r] + bQ);
            }
            union { unsigned short us[4]; uint2 u2; } pk;
            #pragma unroll
            for (int r = 0; r < 4; ++r) pk.us[r] = f2bf(dV[r] + bV);
            *(uint2*)&Vs[ct * 16 + lr][n4] = pk.u2;   // packed 8B, key-contig
        }
    }
    __syncthreads();

    bf16x8 ones;
    #pragma unroll
    for (int j = 0; j < 8; ++j) ones[j] = (short)0x3F80;   // bf16 1.0

    // ---- dense in-segment attention; wave owns q-tile qt ----
    for (int qt = wv; qt < NT; qt += 4) {
        const bf16x8 qf0 = *(const bf16x8*)&Qs[qt * 16 + lr][lg * 8];
        const bf16x8 qf1 = *(const bf16x8*)&Qs[qt * 16 + lr][32 + lg * 8];
        for (int kt = 0; kt < 2 * KB; ++kt) {
            if (kt < NT) {
                const bf16x8 kf0 = *(const bf16x8*)&Ks[kt * 16 + lr][lg * 8];
                const bf16x8 kf1 = *(const bf16x8*)&Ks[kt * 16 + lr][32 + lg * 8];
                f32x4 dsc = {0.f, 0.f, 0.f, 0.f};
                dsc = __builtin_amdgcn_mfma_f32_16x16x32_bf16(qf0, kf0, dsc, 0, 0, 0);
                dsc = __builtin_amdgcn_mfma_f32_16x16x32_bf16(qf1, kf1, dsc, 0, 0, 0);
                const bool valid = (kt * 16 + lr) < R;   // uniform in-segment mask
                #pragma unroll
                for (int r = 0; r < 4; ++r)
                    Ps[qt * 16 + lg * 4 + r][kt * 16 + lr] =
                        valid ? f2bf(__expf(dsc[r] * SCALE)) : 0;
            } else {
                #pragma unroll
                for (int r = 0; r < 4; ++r)
                    Ps[qt * 16 + lg * 4 + r][kt * 16 + lr] = 0;
            }
        }
        asm volatile("s_waitcnt lgkmcnt(0)" ::: "memory");  // same-wave LDS RAW

        f32x4 o0 = {0,0,0,0}, o1 = {0,0,0,0}, o2 = {0,0,0,0}, o3 = {0,0,0,0};
        f32x4 sac = {0,0,0,0};
        for (int kb = 0; kb < KB; ++kb) {
            const bf16x8 pa = *(const bf16x8*)&Ps[qt * 16 + lr][kb * 32 + lg * 8];
            sac = __builtin_amdgcn_mfma_f32_16x16x32_bf16(pa, ones, sac, 0, 0, 0);
            const bf16x8 v0 = *(const bf16x8*)&Vs[lr][kb * 32 + lg * 8];
            const bf16x8 v1 = *(const bf16x8*)&Vs[16 + lr][kb * 32 + lg * 8];
            const bf16x8 v2 = *(const bf16x8*)&Vs[32 + lr][kb * 32 + lg * 8];
            const bf16x8 v3 = *(const bf16x8*)&Vs[48 + lr][kb * 32 + lg * 8];
            o0 = __builtin_amdgcn_mfma_f32_16x16x32_bf16(pa, v0, o0, 0, 0, 0);
            o1 = __builtin_amdgcn_mfma_f32_16x16x32_bf16(pa, v1, o1, 0, 0, 0);
            o2 = __builtin_amdgcn_mfma_f32_16x16x32_bf16(pa, v2, o2, 0, 0, 0);
            o3 = __builtin_amdgcn_mfma_f32_16x16x32_bf16(pa, v3, o3, 0, 0, 0);
        }

        // ---- epilogue: normalize, bounce O through this qt's (dead) Ps rows,
        // then coalesced 16B-per-lane global stores ----
        #pragma unroll
        for (int r = 0; r < 4; ++r) {
            const float inv = 1.f / sac[r];
            const int q = qt * 16 + lg * 4 + r;
            Ps[q][lr]      = f2bf(o0[r] * inv);
            Ps[q][16 + lr] = f2bf(o1[r] * inv);
            Ps[q][32 + lr] = f2bf(o2[r] * inv);
            Ps[q][48 + lr] = f2bf(o3[r] * inv);
        }
        asm volatile("s_waitcnt lgkmcnt(0)" ::: "memory");  // same-wave LDS RAW
        #pragma unroll
        for (int pass = 0; pass < 2; ++pass) {
            const int qi = pass * 8 + (lane >> 3);    // row within tile, 0..15
            const int q  = qt * 16 + qi;
            const int dd = (lane & 7) * 8;
            if (q < R)
                *(bf16x8*)(attb + (size_t)(s + q) * D + h * 64 + dd) =
                    *(const bf16x8*)&Ps[q][dd];
        }
    }

    // ---- per-segment completion: 8th block does LN2 + out-projection ----
    __syncthreads();   // all waves' attb stores drained (vmcnt at barrier)
    if (t == 0) {
        const int old = __hip_atomic_fetch_add(&cnt[b], 1, __ATOMIC_ACQ_REL,
                                               __HIP_MEMORY_SCOPE_AGENT);
        amWinner = (old == H - 1);
    }
    __syncthreads();
    if (!amWinner) return;

    // winner: LN2 over D=512 + out-proj for rows [s, s+R), tile by tile.
    // h2 overlays dead Ps (8320 shorts == 16*520 exactly).
    unsigned short (*h2)[520] = (unsigned short(*)[520])&Ps[0][0];
    const float4 ga = *(const float4*)&ln2g[lane * 8];
    const float4 gb = *(const float4*)&ln2g[lane * 8 + 4];
    const float4 ba = *(const float4*)&ln2b[lane * 8];
    const float4 bb = *(const float4*)&ln2b[lane * 8 + 4];
    const float gv[8] = {ga.x, ga.y, ga.z, ga.w, gb.x, gb.y, gb.z, gb.w};
    const float bv[8] = {ba.x, ba.y, ba.z, ba.w, bb.x, bb.y, bb.z, bb.w};
    const float bo = b_out[wv * 16 + lr];

    for (int qt = 0; qt < NT; ++qt) {
        #pragma unroll
        for (int i = 0; i < 4; ++i) {
            const int rr = wv * 4 + i;                 // row within tile
            int row = s + qt * 16 + rr;
            row = row < N ? row : N - 1;               // clamp; pad rows junk
            const bf16x8 v8 = *(const bf16x8*)(attb + (size_t)row * D + lane * 8);
            float vals[8];
            float sm = 0.f, sq = 0.f;
            #pragma unroll
            for (int c = 0; c < 8; ++c) {
                vals[c] = bf2f((unsigned short)v8[c]);
                sm += vals[c];
                sq += vals[c] * vals[c];
            }
            #pragma unroll
            for (int off = 1; off < 64; off <<= 1) {
                sm += __shfl_xor(sm, off);
                sq += __shfl_xor(sq, off);
            }
            const float mean = sm * (1.f / 512.f);
            const float var  = sq * (1.f / 512.f) - mean * mean;
            const float rstd = rsqrtf(var + EPS);
            bf16x8 hv;
            #pragma unroll
            for (int c = 0; c < 8; ++c)
                hv[c] = (short)f2bf((vals[c] - mean) * rstd * gv[c] + bv[c]);
            *(bf16x8*)&h2[rr][lane * 8] = hv;
        }
        __syncthreads();

        f32x4 acc = {0.f, 0.f, 0.f, 0.f};
        #pragma unroll
        for (int ks = 0; ks < 16; ++ks) {
            const bf16x8 a  = *(const bf16x8*)&h2[lr][ks * 32 + lg * 8];
            const bf16x8 wb = *(const bf16x8*)&Wot[(size_t)(wv * 16 + lr) * D + ks * 32 + lg * 8];
            acc = __builtin_amdgcn_mfma_f32_16x16x32_bf16(a, wb, acc, 0, 0, 0);
        }
        #pragma unroll
        for (int r = 0; r < 4; ++r) {
            const int q = qt * 16 + lg * 4 + r;
            if (q < R)                                  // NaN pad rows guarded
                y[(size_t)(s + q) * 64 + wv * 16 + lr] = acc[r] + bo;
        }
        __syncthreads();   // h2 reused next tile
    }
}

// ---------------------------------------------------------------------------
extern "C" void kernel_launch(void* const* d_in, const int* in_sizes, int n_in,
                              void* d_out, int out_size, void* d_ws, size_t ws_size,
                              hipStream_t stream) {
    const float* x     = (const float*)d_in[0];
    const int*   batch = (const int*)  d_in[1];
    const float* ln1_g = (const float*)d_in[2];
    const float* ln1_b = (const float*)d_in[3];
    const float* W_qkv = (const float*)d_in[4];
    const float* b_qkv = (const float*)d_in[5];
    const float* ln2_g = (const float*)d_in[6];
    const float* ln2_b = (const float*)d_in[7];
    const float* W_out = (const float*)d_in[8];
    const float* b_out = (const float*)d_in[9];
    float* y = (float*)d_out;

    unsigned short* Wt   = (unsigned short*)d_ws;         // [1536][64] bf16
    unsigned short* Wot  = Wt  + (size_t)TD * 64;         // [64][512] bf16
    unsigned short* h1g  = Wot + (size_t)64 * D;          // [N][64] bf16
    unsigned short* attb = h1g + (size_t)N * 64;          // [N][512] bf16
    int* bound = (int*)(attb + (size_t)N * D);            // [257]
    int* cnt   = bound + 257;                             // [256] (re-zeroed)

    hipLaunchKernelGGL(prep_kernel, dim3(1568), dim3(256), 0, stream,
                       x, ln1_g, ln1_b, W_qkv, W_out, batch, Wt, Wot, bound,
                       h1g, cnt);
    hipLaunchKernelGGL(seghead_kernel, dim3(256, 8), dim3(256), 0, stream,
                       h1g, Wt, b_qkv, bound, attb, ln2_g, ln2_b, Wot, b_out,
                       y, cnt);
}

// Round 13
// 34.225 us; speedup vs baseline: 2.6281x; 2.6281x over previous
//
#include <hip/hip_runtime.h>
#include <math.h>

#define N 6144
#define E 64
#define H 8
#define D 512
#define TD 1536  // 3*D
#define EPS 1e-5f
#define SCALE 0.04419417382415922f  // 1/sqrt(512)
#define RMAX 64   // max segment size; multinomial max ~41, P(>64) ~1e-14

typedef __attribute__((ext_vector_type(8))) short bf16x8;
typedef __attribute__((ext_vector_type(4))) float f32x4;

static __device__ __forceinline__ unsigned short f2bf(float f) {
    union { float f; unsigned int u; } v; v.f = f;
    unsigned int r = v.u + 0x7FFFu + ((v.u >> 16) & 1u);  // RNE
    return (unsigned short)(r >> 16);
}
static __device__ __forceinline__ float bf2f(unsigned short u) {
    union { unsigned int u; float f; } v; v.u = ((unsigned int)u) << 16;
    return v.f;
}

// ---------------------------------------------------------------------------
// Kernel 0: prep. Blocks [0,32): bound table + Wt/Wot bf16 transposes.
// Blocks [32,1568): LN1 -> h1 bf16 [N][64], one row per wave (full
// parallelism — R10 lesson: per-block LN1 recompute regressed 35->44).
// ---------------------------------------------------------------------------
__global__ __launch_bounds__(256) void prep_kernel(
    const float* __restrict__ x, const float* __restrict__ ln1g,
    const float* __restrict__ ln1b, const float* __restrict__ W_qkv,
    const float* __restrict__ W_out, const int* __restrict__ batch,
    unsigned short* __restrict__ Wt, unsigned short* __restrict__ Wot,
    int* __restrict__ bound, unsigned short* __restrict__ h1g)
{
    const int t = threadIdx.x, lane = t & 63, wv = t >> 6;
    if (blockIdx.x < 32) {
        const int tid = blockIdx.x * 256 + t;
        if (tid < N) {
            const int bv = batch[tid];
            const int prev = tid ? batch[tid - 1] : -1;
            if (bv != prev)
                for (int v = prev + 1; v <= bv; ++v) bound[v] = tid;
            if (tid == N - 1)
                for (int v = bv + 1; v <= 256; ++v) bound[v] = N;
        }
        for (int i = tid; i < 64 * TD; i += 8192) {    // Wt[j][k] = W[k][j]
            const int k = i / TD, j = i - k * TD;
            Wt[j * 64 + k] = f2bf(W_qkv[i]);
        }
        for (int i = tid; i < 512 * 64; i += 8192) {   // Wot[j][k] = Wo[k][j]
            const int k = i >> 6, j = i & 63;
            Wot[j * 512 + k] = f2bf(W_out[i]);
        }
    } else {
        const int row = (blockIdx.x - 32) * 4 + wv;    // [0, 6144)
        const float v = x[(size_t)row * E + lane];
        float sm = v, sq = v * v;
        #pragma unroll
        for (int off = 1; off < 64; off <<= 1) {
            sm += __shfl_xor(sm, off);
            sq += __shfl_xor(sq, off);
        }
        const float mean = sm * (1.f / 64.f);
        const float var  = sq * (1.f / 64.f) - mean * mean;
        h1g[(size_t)row * 64 + lane] =
            f2bf((v - mean) * rsqrtf(var + EPS) * ln1g[lane] + ln1b[lane]);
    }
}

// ---------------------------------------------------------------------------
// Kernel 1: one block per (segment, head). Wave wv owns column-tile ct=wv of
// K,Q,V; one sync; dense in-segment attention; O bounced through dead Ps
// rows for coalesced 16B stores. RMAX=64 -> 36.9 KB LDS -> 4 blocks/CU
// (was 53 KB / 3). Structural fusion ruled out by measurement: grid-sync
// (R5, +210us) and agent-scope winner atomics (R12, +55us) both regress.
// Frag maps (verified R3-R11): A[row=lr][k=lg*8+j], B[col=lr][k=lg*8+j],
// D[col=lr][row=lg*4+r].
// ---------------------------------------------------------------------------
__global__ __launch_bounds__(256) void seghead_kernel(
    const unsigned short* __restrict__ h1g, const unsigned short* __restrict__ Wt,
    const float* __restrict__ b_qkv, const int* __restrict__ bound,
    unsigned short* __restrict__ attb)
{
    __shared__ unsigned short Qs[RMAX][72];     // per-head Q [q][d]   9 KB
    __shared__ unsigned short Ks[RMAX][72];     // per-head K [key][d] 9 KB
    __shared__ unsigned short Vs[64][72];       // per-head V^T [d][key] 9 KB
    __shared__ unsigned short Ps[RMAX][72];     // P [q][key] / O bounce 9 KB

    const int t = threadIdx.x, lane = t & 63, wv = t >> 6;
    const int lr = lane & 15, lg = lane >> 4;
    const int b = blockIdx.x, h = blockIdx.y;

    // bound loads first: longest scalar dependency chain (R -> NT/KB/loops)
    const int s = bound[b];
    const int e = bound[b + 1];

    // W fragments for this wave's column tile (overlap under bound latency)
    const int ct = wv;
    const int jK = h * 64 + ct * 16;
    const int jQ = 512 + jK;
    const int jV = 1024 + jK;
    const bf16x8 wK0 = *(const bf16x8*)&Wt[(size_t)(jK + lr) * 64 + lg * 8];
    const bf16x8 wK1 = *(const bf16x8*)&Wt[(size_t)(jK + lr) * 64 + 32 + lg * 8];
    const bf16x8 wQ0 = *(const bf16x8*)&Wt[(size_t)(jQ + lr) * 64 + lg * 8];
    const bf16x8 wQ1 = *(const bf16x8*)&Wt[(size_t)(jQ + lr) * 64 + 32 + lg * 8];
    const bf16x8 wV0 = *(const bf16x8*)&Wt[(size_t)(jV + lr) * 64 + lg * 8];
    const bf16x8 wV1 = *(const bf16x8*)&Wt[(size_t)(jV + lr) * 64 + 32 + lg * 8];
    const float bK = b_qkv[jK + lr];
    const float bQ = b_qkv[jQ + lr];
    const float bV = b_qkv[jV + lr];

    int R = e - s;
    if (R <= 0) return;
    if (R > RMAX) R = RMAX;             // safety clamp (P ~ 1e-14)
    const int NT = (R + 15) >> 4;       // 16-row tiles (1..4)
    const int RT = NT * 16;
    const int KB = (RT + 31) >> 5;      // 32-key blocks (1..2)

    // zero V^T tail key-cols [RT, KB*32): uninitialized LDS there can hold
    // NaN bit-patterns and PV's 0*NaN would poison the accumulator (R7 bug).
    if (RT < KB * 32) {
        for (int idx = t; idx < 64 * 16; idx += 256) {
            const int dd = idx >> 4, cc = RT + (idx & 15);
            if (cc < KB * 32) Vs[dd][cc] = 0;
        }
    }

    // ---- QKV: one pass over row-tiles; K,Q,V together ----
    #pragma unroll
    for (int rt = 0; rt < 4; ++rt) {
        if (rt < NT) {
            int row = s + rt * 16 + lr;
            row = row < N ? row : N - 1;              // clamp (finite data)
            const bf16x8 a0 = *(const bf16x8*)&h1g[(size_t)row * 64 + lg * 8];
            const bf16x8 a1 = *(const bf16x8*)&h1g[(size_t)row * 64 + 32 + lg * 8];
            f32x4 dK = {0,0,0,0}, dQ = {0,0,0,0}, dV = {0,0,0,0};
            dK = __builtin_amdgcn_mfma_f32_16x16x32_bf16(a0, wK0, dK, 0, 0, 0);
            dK = __builtin_amdgcn_mfma_f32_16x16x32_bf16(a1, wK1, dK, 0, 0, 0);
            dQ = __builtin_amdgcn_mfma_f32_16x16x32_bf16(a0, wQ0, dQ, 0, 0, 0);
            dQ = __builtin_amdgcn_mfma_f32_16x16x32_bf16(a1, wQ1, dQ, 0, 0, 0);
            dV = __builtin_amdgcn_mfma_f32_16x16x32_bf16(a0, wV0, dV, 0, 0, 0);
            dV = __builtin_amdgcn_mfma_f32_16x16x32_bf16(a1, wV1, dV, 0, 0, 0);
            const int n4 = rt * 16 + lg * 4;
            #pragma unroll
            for (int r = 0; r < 4; ++r) {
                Ks[n4 + r][ct * 16 + lr] = f2bf(dK[r] + bK);
                Qs[n4 + r][ct * 16 + lr] = f2bf(dQ[r] + bQ);
            }
            union { unsigned short us[4]; uint2 u2; } pk;
            #pragma unroll
            for (int r = 0; r < 4; ++r) pk.us[r] = f2bf(dV[r] + bV);
            *(uint2*)&Vs[ct * 16 + lr][n4] = pk.u2;   // packed 8B, key-contig
        }
    }
    __syncthreads();

    bf16x8 ones;
    #pragma unroll
    for (int j = 0; j < 8; ++j) ones[j] = (short)0x3F80;   // bf16 1.0

    // ---- dense in-segment attention; wave owns q-tile qt (NT<=4) ----
    for (int qt = wv; qt < NT; qt += 4) {
        const bf16x8 qf0 = *(const bf16x8*)&Qs[qt * 16 + lr][lg * 8];
        const bf16x8 qf1 = *(const bf16x8*)&Qs[qt * 16 + lr][32 + lg * 8];
        for (int kt = 0; kt < 2 * KB; ++kt) {
            if (kt < NT) {
                const bf16x8 kf0 = *(const bf16x8*)&Ks[kt * 16 + lr][lg * 8];
                const bf16x8 kf1 = *(const bf16x8*)&Ks[kt * 16 + lr][32 + lg * 8];
                f32x4 dsc = {0.f, 0.f, 0.f, 0.f};
                dsc = __builtin_amdgcn_mfma_f32_16x16x32_bf16(qf0, kf0, dsc, 0, 0, 0);
                dsc = __builtin_amdgcn_mfma_f32_16x16x32_bf16(qf1, kf1, dsc, 0, 0, 0);
                const bool valid = (kt * 16 + lr) < R;   // uniform in-segment mask
                #pragma unroll
                for (int r = 0; r < 4; ++r)
                    Ps[qt * 16 + lg * 4 + r][kt * 16 + lr] =
                        valid ? f2bf(__expf(dsc[r] * SCALE)) : 0;
            } else {
                #pragma unroll
                for (int r = 0; r < 4; ++r)
                    Ps[qt * 16 + lg * 4 + r][kt * 16 + lr] = 0;
            }
        }
        asm volatile("s_waitcnt lgkmcnt(0)" ::: "memory");  // same-wave LDS RAW

        f32x4 o0 = {0,0,0,0}, o1 = {0,0,0,0}, o2 = {0,0,0,0}, o3 = {0,0,0,0};
        f32x4 sac = {0,0,0,0};
        for (int kb = 0; kb < KB; ++kb) {
            const bf16x8 pa = *(const bf16x8*)&Ps[qt * 16 + lr][kb * 32 + lg * 8];
            sac = __builtin_amdgcn_mfma_f32_16x16x32_bf16(pa, ones, sac, 0, 0, 0);
            const bf16x8 v0 = *(const bf16x8*)&Vs[lr][kb * 32 + lg * 8];
            const bf16x8 v1 = *(const bf16x8*)&Vs[16 + lr][kb * 32 + lg * 8];
            const bf16x8 v2 = *(const bf16x8*)&Vs[32 + lr][kb * 32 + lg * 8];
            const bf16x8 v3 = *(const bf16x8*)&Vs[48 + lr][kb * 32 + lg * 8];
            o0 = __builtin_amdgcn_mfma_f32_16x16x32_bf16(pa, v0, o0, 0, 0, 0);
            o1 = __builtin_amdgcn_mfma_f32_16x16x32_bf16(pa, v1, o1, 0, 0, 0);
            o2 = __builtin_amdgcn_mfma_f32_16x16x32_bf16(pa, v2, o2, 0, 0, 0);
            o3 = __builtin_amdgcn_mfma_f32_16x16x32_bf16(pa, v3, o3, 0, 0, 0);
        }

        // ---- epilogue: normalize, bounce O through this qt's (dead) Ps rows,
        // then coalesced 16B-per-lane global stores ----
        #pragma unroll
        for (int r = 0; r < 4; ++r) {
            const float inv = 1.f / sac[r];
            const int q = qt * 16 + lg * 4 + r;
            Ps[q][lr]      = f2bf(o0[r] * inv);
            Ps[q][16 + lr] = f2bf(o1[r] * inv);
            Ps[q][32 + lr] = f2bf(o2[r] * inv);
            Ps[q][48 + lr] = f2bf(o3[r] * inv);
        }
        asm volatile("s_waitcnt lgkmcnt(0)" ::: "memory");  // same-wave LDS RAW
        #pragma unroll
        for (int pass = 0; pass < 2; ++pass) {
            const int qi = pass * 8 + (lane >> 3);    // row within tile, 0..15
            const int q  = qt * 16 + qi;
            const int dd = (lane & 7) * 8;
            if (q < R)
                *(bf16x8*)(attb + (size_t)(s + q) * D + h * 64 + dd) =
                    *(const bf16x8*)&Ps[q][dd];
        }
    }
}

// ---------------------------------------------------------------------------
// Kernel C: LN2 over D=512 + out projection. Vectorized bf16x8 input loads.
// ---------------------------------------------------------------------------
__global__ __launch_bounds__(256) void ln2_out_kernel(
    const unsigned short* __restrict__ att, const float* __restrict__ g,
    const float* __restrict__ b, const unsigned short* __restrict__ Wot,
    const float* __restrict__ bias, float* __restrict__ y)
{
    __shared__ unsigned short h2[16][520];
    const int t = threadIdx.x, lane = t & 63, wv = t >> 6;
    const int row0 = blockIdx.x * 16;
    const int lr = lane & 15, lg = lane >> 4;

    const float4 ga = *(const float4*)&g[lane * 8];
    const float4 gb = *(const float4*)&g[lane * 8 + 4];
    const float4 ba = *(const float4*)&b[lane * 8];
    const float4 bb = *(const float4*)&b[lane * 8 + 4];
    const float gv[8] = {ga.x, ga.y, ga.z, ga.w, gb.x, gb.y, gb.z, gb.w};
    const float bv[8] = {ba.x, ba.y, ba.z, ba.w, bb.x, bb.y, bb.z, bb.w};

    #pragma unroll
    for (int i = 0; i < 4; ++i) {
        const int r = wv * 4 + i;
        const bf16x8 v8 = *(const bf16x8*)(att + (size_t)(row0 + r) * D + lane * 8);
        float vals[8];
        float sm = 0.f, sq = 0.f;
        #pragma unroll
        for (int c = 0; c < 8; ++c) {
            vals[c] = bf2f((unsigned short)v8[c]);
            sm += vals[c];
            sq += vals[c] * vals[c];
        }
        #pragma unroll
        for (int off = 1; off < 64; off <<= 1) {
            sm += __shfl_xor(sm, off);
            sq += __shfl_xor(sq, off);
        }
        const float mean = sm * (1.f / 512.f);
        const float var  = sq * (1.f / 512.f) - mean * mean;
        const float rstd = rsqrtf(var + EPS);
        bf16x8 hv;
        #pragma unroll
        for (int c = 0; c < 8; ++c)
            hv[c] = (short)f2bf((vals[c] - mean) * rstd * gv[c] + bv[c]);
        *(bf16x8*)&h2[r][lane * 8] = hv;              // one 16B LDS store
    }
    __syncthreads();

    const int j0 = wv * 16;
    f32x4 acc = {0.f, 0.f, 0.f, 0.f};
    #pragma unroll
    for (int ks = 0; ks < 16; ++ks) {
        const bf16x8 a  = *(const bf16x8*)&h2[lr][ks * 32 + lg * 8];
        const bf16x8 wb = *(const bf16x8*)&Wot[(size_t)(j0 + lr) * D + ks * 32 + lg * 8];
        acc = __builtin_amdgcn_mfma_f32_16x16x32_bf16(a, wb, acc, 0, 0, 0);
    }
    const float bj = bias[j0 + lr];
    #pragma unroll
    for (int r = 0; r < 4; ++r)
        y[(size_t)(row0 + lg * 4 + r) * 64 + j0 + lr] = acc[r] + bj;
}

// ---------------------------------------------------------------------------
extern "C" void kernel_launch(void* const* d_in, const int* in_sizes, int n_in,
                              void* d_out, int out_size, void* d_ws, size_t ws_size,
                              hipStream_t stream) {
    const float* x     = (const float*)d_in[0];
    const int*   batch = (const int*)  d_in[1];
    const float* ln1_g = (const float*)d_in[2];
    const float* ln1_b = (const float*)d_in[3];
    const float* W_qkv = (const float*)d_in[4];
    const float* b_qkv = (const float*)d_in[5];
    const float* ln2_g = (const float*)d_in[6];
    const float* ln2_b = (const float*)d_in[7];
    const float* W_out = (const float*)d_in[8];
    const float* b_out = (const float*)d_in[9];
    float* y = (float*)d_out;

    unsigned short* Wt   = (unsigned short*)d_ws;         // [1536][64] bf16
    unsigned short* Wot  = Wt  + (size_t)TD * 64;         // [64][512] bf16
    unsigned short* h1g  = Wot + (size_t)64 * D;          // [N][64] bf16
    unsigned short* attb = h1g + (size_t)N * 64;          // [N][512] bf16
    int* bound = (int*)(attb + (size_t)N * D);            // [257]

    hipLaunchKernelGGL(prep_kernel, dim3(1568), dim3(256), 0, stream,
                       x, ln1_g, ln1_b, W_qkv, W_out, batch, Wt, Wot, bound, h1g);
    hipLaunchKernelGGL(seghead_kernel, dim3(256, 8), dim3(256), 0, stream,
                       h1g, Wt, b_qkv, bound, attb);
    hipLaunchKernelGGL(ln2_out_kernel, dim3(N / 16), dim3(256), 0, stream,
                       attb, ln2_g, ln2_b, Wot, b_out, y);
}

// Round 14
// 33.898 us; speedup vs baseline: 2.6534x; 1.0097x over previous
//
#include <hip/hip_runtime.h>
#include <math.h>

#define N 6144
#define E 64
#define H 8
#define D 512
#define TD 1536  // 3*D
#define EPS 1e-5f
#define SCALE 0.04419417382415922f  // 1/sqrt(512)
#define RMAX 64   // max segment size; multinomial max ~41, P(>64) ~1e-14

typedef __attribute__((ext_vector_type(8))) short bf16x8;
typedef __attribute__((ext_vector_type(4))) float f32x4;

static __device__ __forceinline__ unsigned short f2bf(float f) {
    union { float f; unsigned int u; } v; v.f = f;
    unsigned int r = v.u + 0x7FFFu + ((v.u >> 16) & 1u);  // RNE
    return (unsigned short)(r >> 16);
}
static __device__ __forceinline__ float bf2f(unsigned short u) {
    union { unsigned int u; float f; } v; v.u = ((unsigned int)u) << 16;
    return v.f;
}

// ---------------------------------------------------------------------------
// Kernel 0: prep. Blocks [0,32): bound table + Wt/Wot bf16 transposes.
// Blocks [32,1568): LN1 -> h1 bf16 [N][64], one row per wave (full
// parallelism — R10 lesson: per-block LN1 recompute regressed 35->44).
// ---------------------------------------------------------------------------
__global__ __launch_bounds__(256) void prep_kernel(
    const float* __restrict__ x, const float* __restrict__ ln1g,
    const float* __restrict__ ln1b, const float* __restrict__ W_qkv,
    const float* __restrict__ W_out, const int* __restrict__ batch,
    unsigned short* __restrict__ Wt, unsigned short* __restrict__ Wot,
    int* __restrict__ bound, unsigned short* __restrict__ h1g)
{
    const int t = threadIdx.x, lane = t & 63, wv = t >> 6;
    if (blockIdx.x < 32) {
        const int tid = blockIdx.x * 256 + t;
        if (tid < N) {
            const int bv = batch[tid];
            const int prev = tid ? batch[tid - 1] : -1;
            if (bv != prev)
                for (int v = prev + 1; v <= bv; ++v) bound[v] = tid;
            if (tid == N - 1)
                for (int v = bv + 1; v <= 256; ++v) bound[v] = N;
        }
        for (int i = tid; i < 64 * TD; i += 8192) {    // Wt[j][k] = W[k][j]
            const int k = i / TD, j = i - k * TD;
            Wt[j * 64 + k] = f2bf(W_qkv[i]);
        }
        for (int i = tid; i < 512 * 64; i += 8192) {   // Wot[j][k] = Wo[k][j]
            const int k = i >> 6, j = i & 63;
            Wot[j * 512 + k] = f2bf(W_out[i]);
        }
    } else {
        const int row = (blockIdx.x - 32) * 4 + wv;    // [0, 6144)
        const float v = x[(size_t)row * E + lane];
        float sm = v, sq = v * v;
        #pragma unroll
        for (int off = 1; off < 64; off <<= 1) {
            sm += __shfl_xor(sm, off);
            sq += __shfl_xor(sq, off);
        }
        const float mean = sm * (1.f / 64.f);
        const float var  = sq * (1.f / 64.f) - mean * mean;
        h1g[(size_t)row * 64 + lane] =
            f2bf((v - mean) * rsqrtf(var + EPS) * ln1g[lane] + ln1b[lane]);
    }
}

// ---------------------------------------------------------------------------
// Kernel 1: one block per (segment, head). QKV (wave per column-tile), then
// attention with TWO-LEVEL wave split (R13 post-mortem: wave-per-qt left
// half the waves idle for the dominant NT<=2 segments):
//   phase 1: wave per (qt, kt) 16x16 score tile -> Ps; __syncthreads;
//   phase 2: wave per (qt, 32-col half) PV; O bounced through dead Qs
//            (NOT Ps — other waves still read Ps) -> coalesced 16B stores.
// Fusion ruled out by measurement: grid-sync (R5), agent atomics (R12).
// Frag maps (verified R3-R13): A[row=lr][k=lg*8+j], B[col=lr][k=lg*8+j],
// D[col=lr][row=lg*4+r].
// ---------------------------------------------------------------------------
__global__ __launch_bounds__(256) void seghead_kernel(
    const unsigned short* __restrict__ h1g, const unsigned short* __restrict__ Wt,
    const float* __restrict__ b_qkv, const int* __restrict__ bound,
    unsigned short* __restrict__ attb)
{
    __shared__ unsigned short Qs[RMAX][72];     // per-head Q [q][d] / O bounce
    __shared__ unsigned short Ks[RMAX][72];     // per-head K [key][d]
    __shared__ unsigned short Vs[64][72];       // per-head V^T [d][key]
    __shared__ unsigned short Ps[RMAX][72];     // P [q][key]

    const int t = threadIdx.x, lane = t & 63, wv = t >> 6;
    const int lr = lane & 15, lg = lane >> 4;
    const int b = blockIdx.x, h = blockIdx.y;

    // bound loads first: longest scalar dependency chain (R -> NT/KB/loops)
    const int s = bound[b];
    const int e = bound[b + 1];

    // W fragments for this wave's column tile (overlap under bound latency)
    const int ct = wv;
    const int jK = h * 64 + ct * 16;
    const int jQ = 512 + jK;
    const int jV = 1024 + jK;
    const bf16x8 wK0 = *(const bf16x8*)&Wt[(size_t)(jK + lr) * 64 + lg * 8];
    const bf16x8 wK1 = *(const bf16x8*)&Wt[(size_t)(jK + lr) * 64 + 32 + lg * 8];
    const bf16x8 wQ0 = *(const bf16x8*)&Wt[(size_t)(jQ + lr) * 64 + lg * 8];
    const bf16x8 wQ1 = *(const bf16x8*)&Wt[(size_t)(jQ + lr) * 64 + 32 + lg * 8];
    const bf16x8 wV0 = *(const bf16x8*)&Wt[(size_t)(jV + lr) * 64 + lg * 8];
    const bf16x8 wV1 = *(const bf16x8*)&Wt[(size_t)(jV + lr) * 64 + 32 + lg * 8];
    const float bK = b_qkv[jK + lr];
    const float bQ = b_qkv[jQ + lr];
    const float bV = b_qkv[jV + lr];

    int R = e - s;
    if (R <= 0) return;
    if (R > RMAX) R = RMAX;             // safety clamp (P ~ 1e-14)
    const int NT = (R + 15) >> 4;       // 16-row tiles (1..4)
    const int RT = NT * 16;
    const int KB = (RT + 31) >> 5;      // 32-key blocks (1..2)

    // zero V^T tail key-cols [RT, KB*32): uninitialized LDS there can hold
    // NaN bit-patterns and PV's 0*NaN would poison the accumulator (R7 bug).
    if (RT < KB * 32) {
        for (int idx = t; idx < 64 * 16; idx += 256) {
            const int dd = idx >> 4, cc = RT + (idx & 15);
            if (cc < KB * 32) Vs[dd][cc] = 0;
        }
    }

    // ---- QKV: one pass over row-tiles; K,Q,V together ----
    #pragma unroll
    for (int rt = 0; rt < 4; ++rt) {
        if (rt < NT) {
            int row = s + rt * 16 + lr;
            row = row < N ? row : N - 1;              // clamp (finite data)
            const bf16x8 a0 = *(const bf16x8*)&h1g[(size_t)row * 64 + lg * 8];
            const bf16x8 a1 = *(const bf16x8*)&h1g[(size_t)row * 64 + 32 + lg * 8];
            f32x4 dK = {0,0,0,0}, dQ = {0,0,0,0}, dV = {0,0,0,0};
            dK = __builtin_amdgcn_mfma_f32_16x16x32_bf16(a0, wK0, dK, 0, 0, 0);
            dK = __builtin_amdgcn_mfma_f32_16x16x32_bf16(a1, wK1, dK, 0, 0, 0);
            dQ = __builtin_amdgcn_mfma_f32_16x16x32_bf16(a0, wQ0, dQ, 0, 0, 0);
            dQ = __builtin_amdgcn_mfma_f32_16x16x32_bf16(a1, wQ1, dQ, 0, 0, 0);
            dV = __builtin_amdgcn_mfma_f32_16x16x32_bf16(a0, wV0, dV, 0, 0, 0);
            dV = __builtin_amdgcn_mfma_f32_16x16x32_bf16(a1, wV1, dV, 0, 0, 0);
            const int n4 = rt * 16 + lg * 4;
            #pragma unroll
            for (int r = 0; r < 4; ++r) {
                Ks[n4 + r][ct * 16 + lr] = f2bf(dK[r] + bK);
                Qs[n4 + r][ct * 16 + lr] = f2bf(dQ[r] + bQ);
            }
            union { unsigned short us[4]; uint2 u2; } pk;
            #pragma unroll
            for (int r = 0; r < 4; ++r) pk.us[r] = f2bf(dV[r] + bV);
            *(uint2*)&Vs[ct * 16 + lr][n4] = pk.u2;   // packed 8B, key-contig
        }
    }
    __syncthreads();

    bf16x8 ones;
    #pragma unroll
    for (int j = 0; j < 8; ++j) ones[j] = (short)0x3F80;   // bf16 1.0

    const int KT2 = 2 * KB;             // key tiles incl. padding (2 or 4)
    const int ksh = KB;                 // log2(KT2): KB=1->1, KB=2->2

    // ---- phase 1: QK^T score tiles, wave per (qt, kt) 16x16 tile ----
    for (int c = wv; c < NT * KT2; c += 4) {
        const int qt = c >> ksh, kt = c & (KT2 - 1);
        if (kt < NT) {
            const bf16x8 qf0 = *(const bf16x8*)&Qs[qt * 16 + lr][lg * 8];
            const bf16x8 qf1 = *(const bf16x8*)&Qs[qt * 16 + lr][32 + lg * 8];
            const bf16x8 kf0 = *(const bf16x8*)&Ks[kt * 16 + lr][lg * 8];
            const bf16x8 kf1 = *(const bf16x8*)&Ks[kt * 16 + lr][32 + lg * 8];
            f32x4 dsc = {0.f, 0.f, 0.f, 0.f};
            dsc = __builtin_amdgcn_mfma_f32_16x16x32_bf16(qf0, kf0, dsc, 0, 0, 0);
            dsc = __builtin_amdgcn_mfma_f32_16x16x32_bf16(qf1, kf1, dsc, 0, 0, 0);
            const bool valid = (kt * 16 + lr) < R;   // uniform in-segment mask
            #pragma unroll
            for (int r = 0; r < 4; ++r)
                Ps[qt * 16 + lg * 4 + r][kt * 16 + lr] =
                    valid ? f2bf(__expf(dsc[r] * SCALE)) : 0;
        } else {
            #pragma unroll
            for (int r = 0; r < 4; ++r)
                Ps[qt * 16 + lg * 4 + r][kt * 16 + lr] = 0;
        }
    }
    __syncthreads();   // Ps tiles cross waves now

    // ---- phase 2: PV, wave per (qt, 32-d-col half); O -> dead Qs ----
    for (int c = wv; c < NT * 2; c += 4) {
        const int qt = c >> 1, half = c & 1;
        f32x4 oA = {0,0,0,0}, oB = {0,0,0,0}, sac = {0,0,0,0};
        for (int kb = 0; kb < KB; ++kb) {
            const bf16x8 pa = *(const bf16x8*)&Ps[qt * 16 + lr][kb * 32 + lg * 8];
            sac = __builtin_amdgcn_mfma_f32_16x16x32_bf16(pa, ones, sac, 0, 0, 0);
            const bf16x8 vA = *(const bf16x8*)&Vs[half * 32 + lr][kb * 32 + lg * 8];
            const bf16x8 vB = *(const bf16x8*)&Vs[half * 32 + 16 + lr][kb * 32 + lg * 8];
            oA = __builtin_amdgcn_mfma_f32_16x16x32_bf16(pa, vA, oA, 0, 0, 0);
            oB = __builtin_amdgcn_mfma_f32_16x16x32_bf16(pa, vB, oB, 0, 0, 0);
        }
        #pragma unroll
        for (int r = 0; r < 4; ++r) {
            const float inv = 1.f / sac[r];
            const int q = qt * 16 + lg * 4 + r;
            Qs[q][half * 32 + lr]      = f2bf(oA[r] * inv);
            Qs[q][half * 32 + 16 + lr] = f2bf(oB[r] * inv);
        }
        asm volatile("s_waitcnt lgkmcnt(0)" ::: "memory");  // same-wave LDS RAW
        const int qi = lane >> 2;                  // 16 rows x 4 lanes
        const int q  = qt * 16 + qi;
        const int dd = half * 32 + (lane & 3) * 8;
        if (q < R)
            *(bf16x8*)(attb + (size_t)(s + q) * D + h * 64 + dd) =
                *(const bf16x8*)&Qs[q][dd];
    }
}

// ---------------------------------------------------------------------------
// Kernel C: LN2 over D=512 + out projection. Vectorized bf16x8 input loads.
// ---------------------------------------------------------------------------
__global__ __launch_bounds__(256) void ln2_out_kernel(
    const unsigned short* __restrict__ att, const float* __restrict__ g,
    const float* __restrict__ b, const unsigned short* __restrict__ Wot,
    const float* __restrict__ bias, float* __restrict__ y)
{
    __shared__ unsigned short h2[16][520];
    const int t = threadIdx.x, lane = t & 63, wv = t >> 6;
    const int row0 = blockIdx.x * 16;
    const int lr = lane & 15, lg = lane >> 4;

    const float4 ga = *(const float4*)&g[lane * 8];
    const float4 gb = *(const float4*)&g[lane * 8 + 4];
    const float4 ba = *(const float4*)&b[lane * 8];
    const float4 bb = *(const float4*)&b[lane * 8 + 4];
    const float gv[8] = {ga.x, ga.y, ga.z, ga.w, gb.x, gb.y, gb.z, gb.w};
    const float bv[8] = {ba.x, ba.y, ba.z, ba.w, bb.x, bb.y, bb.z, bb.w};

    #pragma unroll
    for (int i = 0; i < 4; ++i) {
        const int r = wv * 4 + i;
        const bf16x8 v8 = *(const bf16x8*)(att + (size_t)(row0 + r) * D + lane * 8);
        float vals[8];
        float sm = 0.f, sq = 0.f;
        #pragma unroll
        for (int c = 0; c < 8; ++c) {
            vals[c] = bf2f((unsigned short)v8[c]);
            sm += vals[c];
            sq += vals[c] * vals[c];
        }
        #pragma unroll
        for (int off = 1; off < 64; off <<= 1) {
            sm += __shfl_xor(sm, off);
            sq += __shfl_xor(sq, off);
        }
        const float mean = sm * (1.f / 512.f);
        const float var  = sq * (1.f / 512.f) - mean * mean;
        const float rstd = rsqrtf(var + EPS);
        bf16x8 hv;
        #pragma unroll
        for (int c = 0; c < 8; ++c)
            hv[c] = (short)f2bf((vals[c] - mean) * rstd * gv[c] + bv[c]);
        *(bf16x8*)&h2[r][lane * 8] = hv;              // one 16B LDS store
    }
    __syncthreads();

    const int j0 = wv * 16;
    f32x4 acc = {0.f, 0.f, 0.f, 0.f};
    #pragma unroll
    for (int ks = 0; ks < 16; ++ks) {
        const bf16x8 a  = *(const bf16x8*)&h2[lr][ks * 32 + lg * 8];
        const bf16x8 wb = *(const bf16x8*)&Wot[(size_t)(j0 + lr) * D + ks * 32 + lg * 8];
        acc = __builtin_amdgcn_mfma_f32_16x16x32_bf16(a, wb, acc, 0, 0, 0);
    }
    const float bj = bias[j0 + lr];
    #pragma unroll
    for (int r = 0; r < 4; ++r)
        y[(size_t)(row0 + lg * 4 + r) * 64 + j0 + lr] = acc[r] + bj;
}

// ---------------------------------------------------------------------------
extern "C" void kernel_launch(void* const* d_in, const int* in_sizes, int n_in,
                              void* d_out, int out_size, void* d_ws, size_t ws_size,
                              hipStream_t stream) {
    const float* x     = (const float*)d_in[0];
    const int*   batch = (const int*)  d_in[1];
    const float* ln1_g = (const float*)d_in[2];
    const float* ln1_b = (const float*)d_in[3];
    const float* W_qkv = (const float*)d_in[4];
    const float* b_qkv = (const float*)d_in[5];
    const float* ln2_g = (const float*)d_in[6];
    const float* ln2_b = (const float*)d_in[7];
    const float* W_out = (const float*)d_in[8];
    const float* b_out = (const float*)d_in[9];
    float* y = (float*)d_out;

    unsigned short* Wt   = (unsigned short*)d_ws;         // [1536][64] bf16
    unsigned short* Wot  = Wt  + (size_t)TD * 64;         // [64][512] bf16
    unsigned short* h1g  = Wot + (size_t)64 * D;          // [N][64] bf16
    unsigned short* attb = h1g + (size_t)N * 64;          // [N][512] bf16
    int* bound = (int*)(attb + (size_t)N * D);            // [257]

    hipLaunchKernelGGL(prep_kernel, dim3(1568), dim3(256), 0, stream,
                       x, ln1_g, ln1_b, W_qkv, W_out, batch, Wt, Wot, bound, h1g);
    hipLaunchKernelGGL(seghead_kernel, dim3(256, 8), dim3(256), 0, stream,
                       h1g, Wt, b_qkv, bound, attb);
    hipLaunchKernelGGL(ln2_out_kernel, dim3(N / 16), dim3(256), 0, stream,
                       attb, ln2_g, ln2_b, Wot, b_out, y);
}

// Round 15
// 32.375 us; speedup vs baseline: 2.7783x; 1.0470x over previous
//
#include <hip/hip_runtime.h>
#include <math.h>

#define N 6144
#define E 64
#define H 8
#define D 512
#define TD 1536  // 3*D
#define EPS 1e-5f
#define SCALE 0.04419417382415922f  // 1/sqrt(512)
#define RMAX 64   // max segment size; multinomial max ~41, P(>64) ~1e-14

typedef __attribute__((ext_vector_type(8))) short bf16x8;
typedef __attribute__((ext_vector_type(4))) float f32x4;

static __device__ __forceinline__ unsigned short f2bf(float f) {
    union { float f; unsigned int u; } v; v.f = f;
    unsigned int r = v.u + 0x7FFFu + ((v.u >> 16) & 1u);  // RNE
    return (unsigned short)(r >> 16);
}
static __device__ __forceinline__ float bf2f(unsigned short u) {
    union { unsigned int u; float f; } v; v.u = ((unsigned int)u) << 16;
    return v.f;
}

// ---------------------------------------------------------------------------
// Kernel 0: prep. Blocks [0,24): bound table. [24,72): Wt transpose — one
// thread per (j, k-octet): 8 coalesced f32 loads + ONE 16B store (R14 wrote
// 2B scatter-stores, 64 lines per instr). [72,88): Wot same scheme.
// [88,1624): LN1 -> h1 bf16 [N][64], one row per wave (R10 lesson: keep LN1
// at full parallelism).
// ---------------------------------------------------------------------------
__global__ __launch_bounds__(256) void prep_kernel(
    const float* __restrict__ x, const float* __restrict__ ln1g,
    const float* __restrict__ ln1b, const float* __restrict__ W_qkv,
    const float* __restrict__ W_out, const int* __restrict__ batch,
    unsigned short* __restrict__ Wt, unsigned short* __restrict__ Wot,
    int* __restrict__ bound, unsigned short* __restrict__ h1g)
{
    const int t = threadIdx.x, lane = t & 63, wv = t >> 6;
    const int bx = blockIdx.x;
    if (bx < 24) {                                     // bound table
        const int tid = bx * 256 + t;
        const int bv = batch[tid];
        const int prev = tid ? batch[tid - 1] : -1;
        if (bv != prev)
            for (int v = prev + 1; v <= bv; ++v) bound[v] = tid;
        if (tid == N - 1)
            for (int v = bv + 1; v <= 256; ++v) bound[v] = N;
    } else if (bx < 72) {                              // Wt[j][k] = W_qkv[k][j]
        const int w = (bx - 24) * 256 + t;             // [0, 12288)
        const int j = w % TD, ko = w / TD;             // ko in [0,8)
        bf16x8 o;
        #pragma unroll
        for (int i = 0; i < 8; ++i)                    // coalesced across j
            o[i] = (short)f2bf(W_qkv[(size_t)(ko * 8 + i) * TD + j]);
        *(bf16x8*)&Wt[(size_t)j * 64 + ko * 8] = o;    // one 16B store
    } else if (bx < 88) {                              // Wot[j][k] = W_out[k][j]
        const int w = (bx - 72) * 256 + t;             // [0, 4096)
        const int j = w & 63, ko = w >> 6;             // ko in [0,64)
        bf16x8 o;
        #pragma unroll
        for (int i = 0; i < 8; ++i)                    // coalesced across j
            o[i] = (short)f2bf(W_out[(size_t)(ko * 8 + i) * 64 + j]);
        *(bf16x8*)&Wot[(size_t)j * 512 + ko * 8] = o;  // one 16B store
    } else {                                           // LN1 rows
        const int row = (bx - 88) * 4 + wv;            // [0, 6144)
        const float v = x[(size_t)row * E + lane];
        float sm = v, sq = v * v;
        #pragma unroll
        for (int off = 1; off < 64; off <<= 1) {
            sm += __shfl_xor(sm, off);
            sq += __shfl_xor(sq, off);
        }
        const float mean = sm * (1.f / 64.f);
        const float var  = sq * (1.f / 64.f) - mean * mean;
        h1g[(size_t)row * 64 + lane] =
            f2bf((v - mean) * rsqrtf(var + EPS) * ln1g[lane] + ln1b[lane]);
    }
}

// ---------------------------------------------------------------------------
// Kernel 1: one block per (segment, head). QKV (wave per column-tile), then
// attention with two-level wave split (R14):
//   phase 1: wave per (qt, kt) 16x16 score tile -> Ps; __syncthreads;
//   phase 2: wave per (qt, 32-col half) PV; O bounced through dead Qs
//            (NOT Ps — other waves still read Ps) -> coalesced 16B stores.
// Fusion ruled out by measurement: grid-sync (R5), agent atomics (R12).
// Frag maps (verified R3-R14): A[row=lr][k=lg*8+j], B[col=lr][k=lg*8+j],
// D[col=lr][row=lg*4+r].
// ---------------------------------------------------------------------------
__global__ __launch_bounds__(256) void seghead_kernel(
    const unsigned short* __restrict__ h1g, const unsigned short* __restrict__ Wt,
    const float* __restrict__ b_qkv, const int* __restrict__ bound,
    unsigned short* __restrict__ attb)
{
    __shared__ unsigned short Qs[RMAX][72];     // per-head Q [q][d] / O bounce
    __shared__ unsigned short Ks[RMAX][72];     // per-head K [key][d]
    __shared__ unsigned short Vs[64][72];       // per-head V^T [d][key]
    __shared__ unsigned short Ps[RMAX][72];     // P [q][key]

    const int t = threadIdx.x, lane = t & 63, wv = t >> 6;
    const int lr = lane & 15, lg = lane >> 4;
    const int b = blockIdx.x, h = blockIdx.y;

    // bound loads first: longest scalar dependency chain (R -> NT/KB/loops)
    const int s = bound[b];
    const int e = bound[b + 1];

    // W fragments for this wave's column tile (overlap under bound latency)
    const int ct = wv;
    const int jK = h * 64 + ct * 16;
    const int jQ = 512 + jK;
    const int jV = 1024 + jK;
    const bf16x8 wK0 = *(const bf16x8*)&Wt[(size_t)(jK + lr) * 64 + lg * 8];
    const bf16x8 wK1 = *(const bf16x8*)&Wt[(size_t)(jK + lr) * 64 + 32 + lg * 8];
    const bf16x8 wQ0 = *(const bf16x8*)&Wt[(size_t)(jQ + lr) * 64 + lg * 8];
    const bf16x8 wQ1 = *(const bf16x8*)&Wt[(size_t)(jQ + lr) * 64 + 32 + lg * 8];
    const bf16x8 wV0 = *(const bf16x8*)&Wt[(size_t)(jV + lr) * 64 + lg * 8];
    const bf16x8 wV1 = *(const bf16x8*)&Wt[(size_t)(jV + lr) * 64 + 32 + lg * 8];
    const float bK = b_qkv[jK + lr];
    const float bQ = b_qkv[jQ + lr];
    const float bV = b_qkv[jV + lr];

    int R = e - s;
    if (R <= 0) return;
    if (R > RMAX) R = RMAX;             // safety clamp (P ~ 1e-14)
    const int NT = (R + 15) >> 4;       // 16-row tiles (1..4)
    const int RT = NT * 16;
    const int KB = (RT + 31) >> 5;      // 32-key blocks (1..2)

    // zero V^T tail key-cols [RT, KB*32): uninitialized LDS there can hold
    // NaN bit-patterns and PV's 0*NaN would poison the accumulator (R7 bug).
    if (RT < KB * 32) {
        for (int idx = t; idx < 64 * 16; idx += 256) {
            const int dd = idx >> 4, cc = RT + (idx & 15);
            if (cc < KB * 32) Vs[dd][cc] = 0;
        }
    }

    // ---- QKV: one pass over row-tiles; K,Q,V together ----
    #pragma unroll
    for (int rt = 0; rt < 4; ++rt) {
        if (rt < NT) {
            int row = s + rt * 16 + lr;
            row = row < N ? row : N - 1;              // clamp (finite data)
            const bf16x8 a0 = *(const bf16x8*)&h1g[(size_t)row * 64 + lg * 8];
            const bf16x8 a1 = *(const bf16x8*)&h1g[(size_t)row * 64 + 32 + lg * 8];
            f32x4 dK = {0,0,0,0}, dQ = {0,0,0,0}, dV = {0,0,0,0};
            dK = __builtin_amdgcn_mfma_f32_16x16x32_bf16(a0, wK0, dK, 0, 0, 0);
            dK = __builtin_amdgcn_mfma_f32_16x16x32_bf16(a1, wK1, dK, 0, 0, 0);
            dQ = __builtin_amdgcn_mfma_f32_16x16x32_bf16(a0, wQ0, dQ, 0, 0, 0);
            dQ = __builtin_amdgcn_mfma_f32_16x16x32_bf16(a1, wQ1, dQ, 0, 0, 0);
            dV = __builtin_amdgcn_mfma_f32_16x16x32_bf16(a0, wV0, dV, 0, 0, 0);
            dV = __builtin_amdgcn_mfma_f32_16x16x32_bf16(a1, wV1, dV, 0, 0, 0);
            const int n4 = rt * 16 + lg * 4;
            #pragma unroll
            for (int r = 0; r < 4; ++r) {
                Ks[n4 + r][ct * 16 + lr] = f2bf(dK[r] + bK);
                Qs[n4 + r][ct * 16 + lr] = f2bf(dQ[r] + bQ);
            }
            union { unsigned short us[4]; uint2 u2; } pk;
            #pragma unroll
            for (int r = 0; r < 4; ++r) pk.us[r] = f2bf(dV[r] + bV);
            *(uint2*)&Vs[ct * 16 + lr][n4] = pk.u2;   // packed 8B, key-contig
        }
    }
    __syncthreads();

    bf16x8 ones;
    #pragma unroll
    for (int j = 0; j < 8; ++j) ones[j] = (short)0x3F80;   // bf16 1.0

    const int KT2 = 2 * KB;             // key tiles incl. padding (2 or 4)
    const int ksh = KB;                 // log2(KT2): KB=1->1, KB=2->2

    // ---- phase 1: QK^T score tiles, wave per (qt, kt) 16x16 tile ----
    for (int c = wv; c < NT * KT2; c += 4) {
        const int qt = c >> ksh, kt = c & (KT2 - 1);
        if (kt < NT) {
            const bf16x8 qf0 = *(const bf16x8*)&Qs[qt * 16 + lr][lg * 8];
            const bf16x8 qf1 = *(const bf16x8*)&Qs[qt * 16 + lr][32 + lg * 8];
            const bf16x8 kf0 = *(const bf16x8*)&Ks[kt * 16 + lr][lg * 8];
            const bf16x8 kf1 = *(const bf16x8*)&Ks[kt * 16 + lr][32 + lg * 8];
            f32x4 dsc = {0.f, 0.f, 0.f, 0.f};
            dsc = __builtin_amdgcn_mfma_f32_16x16x32_bf16(qf0, kf0, dsc, 0, 0, 0);
            dsc = __builtin_amdgcn_mfma_f32_16x16x32_bf16(qf1, kf1, dsc, 0, 0, 0);
            const bool valid = (kt * 16 + lr) < R;   // uniform in-segment mask
            #pragma unroll
            for (int r = 0; r < 4; ++r)
                Ps[qt * 16 + lg * 4 + r][kt * 16 + lr] =
                    valid ? f2bf(__expf(dsc[r] * SCALE)) : 0;
        } else {
            #pragma unroll
            for (int r = 0; r < 4; ++r)
                Ps[qt * 16 + lg * 4 + r][kt * 16 + lr] = 0;
        }
    }
    __syncthreads();   // Ps tiles cross waves now

    // ---- phase 2: PV, wave per (qt, 32-d-col half); O -> dead Qs ----
    for (int c = wv; c < NT * 2; c += 4) {
        const int qt = c >> 1, half = c & 1;
        f32x4 oA = {0,0,0,0}, oB = {0,0,0,0}, sac = {0,0,0,0};
        for (int kb = 0; kb < KB; ++kb) {
            const bf16x8 pa = *(const bf16x8*)&Ps[qt * 16 + lr][kb * 32 + lg * 8];
            sac = __builtin_amdgcn_mfma_f32_16x16x32_bf16(pa, ones, sac, 0, 0, 0);
            const bf16x8 vA = *(const bf16x8*)&Vs[half * 32 + lr][kb * 32 + lg * 8];
            const bf16x8 vB = *(const bf16x8*)&Vs[half * 32 + 16 + lr][kb * 32 + lg * 8];
            oA = __builtin_amdgcn_mfma_f32_16x16x32_bf16(pa, vA, oA, 0, 0, 0);
            oB = __builtin_amdgcn_mfma_f32_16x16x32_bf16(pa, vB, oB, 0, 0, 0);
        }
        #pragma unroll
        for (int r = 0; r < 4; ++r) {
            const float inv = 1.f / sac[r];
            const int q = qt * 16 + lg * 4 + r;
            Qs[q][half * 32 + lr]      = f2bf(oA[r] * inv);
            Qs[q][half * 32 + 16 + lr] = f2bf(oB[r] * inv);
        }
        asm volatile("s_waitcnt lgkmcnt(0)" ::: "memory");  // same-wave LDS RAW
        const int qi = lane >> 2;                  // 16 rows x 4 lanes
        const int q  = qt * 16 + qi;
        const int dd = half * 32 + (lane & 3) * 8;
        if (q < R)
            *(bf16x8*)(attb + (size_t)(s + q) * D + h * 64 + dd) =
                *(const bf16x8*)&Qs[q][dd];
    }
}

// ---------------------------------------------------------------------------
// Kernel C: LN2 over D=512 + out projection. Vectorized bf16x8 input loads;
// K=512 accumulation split into two independent 8-deep MFMA chains (ILP).
// ---------------------------------------------------------------------------
__global__ __launch_bounds__(256) void ln2_out_kernel(
    const unsigned short* __restrict__ att, const float* __restrict__ g,
    const float* __restrict__ b, const unsigned short* __restrict__ Wot,
    const float* __restrict__ bias, float* __restrict__ y)
{
    __shared__ unsigned short h2[16][520];
    const int t = threadIdx.x, lane = t & 63, wv = t >> 6;
    const int row0 = blockIdx.x * 16;
    const int lr = lane & 15, lg = lane >> 4;

    const float4 ga = *(const float4*)&g[lane * 8];
    const float4 gb = *(const float4*)&g[lane * 8 + 4];
    const float4 ba = *(const float4*)&b[lane * 8];
    const float4 bb = *(const float4*)&b[lane * 8 + 4];
    const float gv[8] = {ga.x, ga.y, ga.z, ga.w, gb.x, gb.y, gb.z, gb.w};
    const float bv[8] = {ba.x, ba.y, ba.z, ba.w, bb.x, bb.y, bb.z, bb.w};

    #pragma unroll
    for (int i = 0; i < 4; ++i) {
        const int r = wv * 4 + i;
        const bf16x8 v8 = *(const bf16x8*)(att + (size_t)(row0 + r) * D + lane * 8);
        float vals[8];
        float sm = 0.f, sq = 0.f;
        #pragma unroll
        for (int c = 0; c < 8; ++c) {
            vals[c] = bf2f((unsigned short)v8[c]);
            sm += vals[c];
            sq += vals[c] * vals[c];
        }
        #pragma unroll
        for (int off = 1; off < 64; off <<= 1) {
            sm += __shfl_xor(sm, off);
            sq += __shfl_xor(sq, off);
        }
        const float mean = sm * (1.f / 512.f);
        const float var  = sq * (1.f / 512.f) - mean * mean;
        const float rstd = rsqrtf(var + EPS);
        bf16x8 hv;
        #pragma unroll
        for (int c = 0; c < 8; ++c)
            hv[c] = (short)f2bf((vals[c] - mean) * rstd * gv[c] + bv[c]);
        *(bf16x8*)&h2[r][lane * 8] = hv;              // one 16B LDS store
    }
    __syncthreads();

    const int j0 = wv * 16;
    f32x4 acc0 = {0.f, 0.f, 0.f, 0.f};
    f32x4 acc1 = {0.f, 0.f, 0.f, 0.f};
    #pragma unroll
    for (int ks = 0; ks < 8; ++ks) {
        const bf16x8 a0 = *(const bf16x8*)&h2[lr][ks * 32 + lg * 8];
        const bf16x8 w0 = *(const bf16x8*)&Wot[(size_t)(j0 + lr) * D + ks * 32 + lg * 8];
        acc0 = __builtin_amdgcn_mfma_f32_16x16x32_bf16(a0, w0, acc0, 0, 0, 0);
        const bf16x8 a1 = *(const bf16x8*)&h2[lr][(ks + 8) * 32 + lg * 8];
        const bf16x8 w1 = *(const bf16x8*)&Wot[(size_t)(j0 + lr) * D + (ks + 8) * 32 + lg * 8];
        acc1 = __builtin_amdgcn_mfma_f32_16x16x32_bf16(a1, w1, acc1, 0, 0, 0);
    }
    const f32x4 acc = acc0 + acc1;
    const float bj = bias[j0 + lr];
    #pragma unroll
    for (int r = 0; r < 4; ++r)
        y[(size_t)(row0 + lg * 4 + r) * 64 + j0 + lr] = acc[r] + bj;
}

// ---------------------------------------------------------------------------
extern "C" void kernel_launch(void* const* d_in, const int* in_sizes, int n_in,
                              void* d_out, int out_size, void* d_ws, size_t ws_size,
                              hipStream_t stream) {
    const float* x     = (const float*)d_in[0];
    const int*   batch = (const int*)  d_in[1];
    const float* ln1_g = (const float*)d_in[2];
    const float* ln1_b = (const float*)d_in[3];
    const float* W_qkv = (const float*)d_in[4];
    const float* b_qkv = (const float*)d_in[5];
    const float* ln2_g = (const float*)d_in[6];
    const float* ln2_b = (const float*)d_in[7];
    const float* W_out = (const float*)d_in[8];
    const float* b_out = (const float*)d_in[9];
    float* y = (float*)d_out;

    unsigned short* Wt   = (unsigned short*)d_ws;         // [1536][64] bf16
    unsigned short* Wot  = Wt  + (size_t)TD * 64;         // [64][512] bf16
    unsigned short* h1g  = Wot + (size_t)64 * D;          // [N][64] bf16
    unsigned short* attb = h1g + (size_t)N * 64;          // [N][512] bf16
    int* bound = (int*)(attb + (size_t)N * D);            // [257]

    hipLaunchKernelGGL(prep_kernel, dim3(1624), dim3(256), 0, stream,
                       x, ln1_g, ln1_b, W_qkv, W_out, batch, Wt, Wot, bound, h1g);
    hipLaunchKernelGGL(seghead_kernel, dim3(256, 8), dim3(256), 0, stream,
                       h1g, Wt, b_qkv, bound, attb);
    hipLaunchKernelGGL(ln2_out_kernel, dim3(N / 16), dim3(256), 0, stream,
                       attb, ln2_g, ln2_b, Wot, b_out, y);
}